// Round 1
// baseline (37.640 us; speedup 1.0000x reference)
//
#include <hip/hip_runtime.h>
#include <math.h>

#define HDIM 2048
#define NEXP 8
#define TB 4                       // tokens per wave
#define WPB 4                      // waves per block
#define TPB (TB * WPB)             // tokens per block = 16

// ---------------------------------------------------------------------------
// Main router kernel: one wave handles TB tokens.
// Lanes split H; each lane accumulates partial dot(x[t], W[e]) for all
// (t,e) pairs, then a shuffle "transpose reduce" leaves lane l holding
// logit(token (l&31)>>3, expert l&7). Top-2 + softmax in-register.
// ---------------------------------------------------------------------------
__global__ void router_main(const float* __restrict__ x,
                            const float* __restrict__ W,
                            float* __restrict__ out_scores,   // [T,2]
                            float* __restrict__ out_idx,      // [T,2] as float
                            float* __restrict__ hist_global,  // [8] (fallback)
                            float* __restrict__ partial,      // [nblocks,8] or null
                            int T)
{
    __shared__ int cnt[NEXP];
    if (threadIdx.x < NEXP) cnt[threadIdx.x] = 0;
    __syncthreads();

    const int lane  = threadIdx.x & 63;
    const int wv    = threadIdx.x >> 6;
    const int gwave = blockIdx.x * WPB + wv;
    const int tok0  = gwave * TB;

    float acc[TB * NEXP];
#pragma unroll
    for (int i = 0; i < TB * NEXP; ++i) acc[i] = 0.f;

    // ---- gating matmul: H split across lanes, float4 per lane per iter ----
#pragma unroll
    for (int iter = 0; iter < HDIM / 256; ++iter) {
        const int h = iter * 256 + lane * 4;
        float4 w[NEXP];
#pragma unroll
        for (int e = 0; e < NEXP; ++e)
            w[e] = *reinterpret_cast<const float4*>(W + e * HDIM + h);
#pragma unroll
        for (int t = 0; t < TB; ++t) {
            const int tt = min(tok0 + t, T - 1);   // clamp keeps loads in-bounds
            float4 xv = *reinterpret_cast<const float4*>(x + (size_t)tt * HDIM + h);
#pragma unroll
            for (int e = 0; e < NEXP; ++e) {
                float a = acc[t * NEXP + e];
                a = fmaf(xv.x, w[e].x, a);
                a = fmaf(xv.y, w[e].y, a);
                a = fmaf(xv.z, w[e].z, a);
                a = fmaf(xv.w, w[e].w, a);
                acc[t * NEXP + e] = a;
            }
        }
    }

    // ---- transpose reduce: 32 values over 64 lanes, all static indices ----
#pragma unroll
    for (int j = 0; j < 32; ++j) acc[j] += __shfl_xor(acc[j], 32, 64);

#define FOLD(SM)                                                          \
    {                                                                     \
        const bool up = (lane & SM) != 0;                                 \
        _Pragma("unroll")                                                 \
        for (int j = 0; j < SM; ++j) {                                    \
            float keep = up ? acc[j + SM] : acc[j];                       \
            float send = up ? acc[j] : acc[j + SM];                       \
            acc[j] = keep + __shfl_xor(send, SM, 64);                     \
        }                                                                 \
    }
    FOLD(16) FOLD(8) FOLD(4) FOLD(2) FOLD(1)
#undef FOLD

    // lane l now holds logit(token tok0 + ((l&31)>>3), expert l&7)
    const int e_my   = lane & 7;
    const int t_loc  = (lane & 31) >> 3;
    const float mylg = acc[0];

    // ---- top-1 within each aligned 8-lane group (tie -> lower index) ----
    float v1 = mylg;
    int   i1 = e_my;
#pragma unroll
    for (int m = 1; m <= 4; m <<= 1) {
        float ov = __shfl_xor(v1, m, 64);
        int   oi = __shfl_xor(i1, m, 64);
        if (ov > v1 || (ov == v1 && oi < i1)) { v1 = ov; i1 = oi; }
    }
    // ---- top-2: exclude i1, repeat ----
    float v2 = (e_my == i1) ? -3.402823466e+38f : mylg;
    int   i2 = e_my;
#pragma unroll
    for (int m = 1; m <= 4; m <<= 1) {
        float ov = __shfl_xor(v2, m, 64);
        int   oi = __shfl_xor(i2, m, 64);
        if (ov > v2 || (ov == v2 && oi < i2)) { v2 = ov; i2 = oi; }
    }

    // ---- softmax over the 2 selected logits (fp32, stable: v1 >= v2) ----
    const float ed = expf(v2 - v1);
    const float inv = 1.0f / (1.0f + ed);
    const float p0 = inv;
    const float p1 = ed * inv;

    const int tok = tok0 + t_loc;
    const bool leader = (lane < 32) && (e_my == 0) && (tok < T);
    if (leader) {
        out_scores[2 * tok + 0] = p0;
        out_scores[2 * tok + 1] = p1;
        out_idx[2 * tok + 0] = (float)i1;
        out_idx[2 * tok + 1] = (float)i2;
        atomicAdd(&cnt[i1], 1);
        atomicAdd(&cnt[i2], 1);
    }

    __syncthreads();
    if (threadIdx.x < NEXP) {
        if (partial)
            partial[(size_t)blockIdx.x * NEXP + threadIdx.x] = (float)cnt[threadIdx.x];
        else
            atomicAdd(&hist_global[threadIdx.x], (float)cnt[threadIdx.x]);
    }
}

// ---------------------------------------------------------------------------
// Reduce per-block partial counts -> 8 floats. One block, 256 threads.
// ---------------------------------------------------------------------------
__global__ void router_reduce(const float* __restrict__ partial,
                              float* __restrict__ hist, int nblocks)
{
    const int tid  = threadIdx.x;
    const int e    = tid & 7;
    const int g    = tid >> 3;          // 0..31 stripes
    float s = 0.f;
    for (int b = g; b < nblocks; b += 32) s += partial[(size_t)b * NEXP + e];
    s += __shfl_xor(s, 8, 64);
    s += __shfl_xor(s, 16, 64);
    s += __shfl_xor(s, 32, 64);
    __shared__ float sd[4 * NEXP];
    const int wv = tid >> 6, lane = tid & 63;
    if (lane < NEXP) sd[wv * NEXP + lane] = s;
    __syncthreads();
    if (tid < NEXP)
        hist[tid] = sd[tid] + sd[NEXP + tid] + sd[2 * NEXP + tid] + sd[3 * NEXP + tid];
}

__global__ void zero8(float* __restrict__ hist)
{
    if (threadIdx.x < NEXP) hist[threadIdx.x] = 0.f;
}

extern "C" void kernel_launch(void* const* d_in, const int* in_sizes, int n_in,
                              void* d_out, int out_size, void* d_ws, size_t ws_size,
                              hipStream_t stream)
{
    const float* x = (const float*)d_in[0];
    const float* W = (const float*)d_in[1];
    const int T = in_sizes[0] / HDIM;          // 16384

    float* out        = (float*)d_out;
    float* out_scores = out;                   // [T,2]
    float* out_idx    = out + (size_t)2 * T;   // [T,2]
    float* hist       = out + (size_t)4 * T;   // [8]

    const int nblocks = (T + TPB - 1) / TPB;   // 1024
    const bool use_ws = ws_size >= (size_t)nblocks * NEXP * sizeof(float);
    float* partial = use_ws ? (float*)d_ws : nullptr;

    if (!use_ws) zero8<<<1, 64, 0, stream>>>(hist);
    router_main<<<nblocks, 256, 0, stream>>>(x, W, out_scores, out_idx, hist, partial, T);
    if (use_ws) router_reduce<<<1, 256, 0, stream>>>(partial, hist, nblocks);
}